// Round 12
// baseline (2358.193 us; speedup 1.0000x reference)
//
#include <hip/hip_runtime.h>
#include <stdint.h>

// ResidualVQ on MI355X — round 12: fused phases.
// - t1 np-tree fused into the residual update (no separate t1 pass, no final
//   r8 pass; loss from the same values).
// - bf16 residual shadow g_residb: A-frags load pre-packed bf16.
// - q=7 update emits recon directly.
// - CCH=32 (2 tiles/wave), 34 chunk-barriers/q (was 72); next-q chunk0 staged
//   under the update. taskRow LUT kills the rescore off-search.
// Contract (proven rounds 4-11): indices match numpy argmin of
// d = fl(fl(t1+nk) - fl(2*dot)); np-exact pairwise sumsq trees; serial
// ascending-k single-accumulator FMA rescore; stale-threshold prefilter,
// delta = 0.02*sqrt(t1)*sqrt(nkmax) + 3e-4 >= 2*E_bf16.
// g_wb PRE-PERMUTED (16B slot s -> s^(code&7) per 512B code row).

#define NQ      8
#define KCODES  1024
#define DIM     256
#define NVEC    65536
#define ROWS    64
#define CCH     32       // codes per staged chunk (16 KB per buffer)
#define NCH     (KCODES / CCH)   // 32 chunks
#define WARM    2        // min-only chunks (revisited at the end)
#define NITER   (NCH + WARM)
#define CAP     16       // candidate capacity per row per q

typedef unsigned int u32;
typedef unsigned long long u64;
typedef unsigned short u16;
typedef short bf16x8 __attribute__((ext_vector_type(8)));
typedef float f32x4  __attribute__((ext_vector_type(4)));

__device__ float  g_norms[NQ * KCODES];
__device__ u32    g_nkmax;
__device__ double g_loss;
__device__ __align__(16) u16 g_wb[(size_t)NQ * KCODES * DIM];  // permuted bf16
__device__ float  g_resid[(size_t)NVEC * DIM];                 // f32 residual
__device__ __align__(16) u16 g_residb[(size_t)NVEC * DIM];     // bf16 shadow

__device__ __forceinline__ u16 bf16rne(float x){
    u32 u = __float_as_uint(x);
    return (u16)((u + 0x7FFFu + ((u >> 16) & 1u)) >> 16);
}

__device__ __forceinline__ u64 pack4(float4 v){
    return  (u64)bf16rne(v.x)        | ((u64)bf16rne(v.y) << 16)
         | ((u64)bf16rne(v.z) << 32) | ((u64)bf16rne(v.w) << 48);
}

__device__ __forceinline__ void gload_lds16(const void* g, void* l){
    __builtin_amdgcn_global_load_lds(
        (const __attribute__((address_space(1))) u32*)g,
        (__attribute__((address_space(3))) u32*)l, 16, 0, 0);
}

// numpy pairwise sum of squares over 128 contiguous floats (verified round 4)
__device__ __forceinline__ float np_sumsq128(const float* __restrict__ a){
    float r0,r1,r2,r3,r4,r5,r6,r7;
    {
        float4 v0 = *(const float4*)(a);
        float4 v1 = *(const float4*)(a + 4);
        r0 = __fmul_rn(v0.x,v0.x); r1 = __fmul_rn(v0.y,v0.y);
        r2 = __fmul_rn(v0.z,v0.z); r3 = __fmul_rn(v0.w,v0.w);
        r4 = __fmul_rn(v1.x,v1.x); r5 = __fmul_rn(v1.y,v1.y);
        r6 = __fmul_rn(v1.z,v1.z); r7 = __fmul_rn(v1.w,v1.w);
    }
    for (int i = 8; i < 128; i += 8){
        float4 v0 = *(const float4*)(a + i);
        float4 v1 = *(const float4*)(a + i + 4);
        r0 = __fadd_rn(r0, __fmul_rn(v0.x,v0.x));
        r1 = __fadd_rn(r1, __fmul_rn(v0.y,v0.y));
        r2 = __fadd_rn(r2, __fmul_rn(v0.z,v0.z));
        r3 = __fadd_rn(r3, __fmul_rn(v0.w,v0.w));
        r4 = __fadd_rn(r4, __fmul_rn(v1.x,v1.x));
        r5 = __fadd_rn(r5, __fmul_rn(v1.y,v1.y));
        r6 = __fadd_rn(r6, __fmul_rn(v1.z,v1.z));
        r7 = __fadd_rn(r7, __fmul_rn(v1.w,v1.w));
    }
    return __fadd_rn(__fadd_rn(__fadd_rn(r0,r1), __fadd_rn(r2,r3)),
                     __fadd_rn(__fadd_rn(r4,r5), __fadd_rn(r6,r7)));
}

__global__ void vq_zero(){ g_loss = 0.0; g_nkmax = 0u; }

__global__ void vq_norms_np(const float* __restrict__ cb){
    int row = blockIdx.x * 256 + threadIdx.x;               // 8192 rows
    const float* a = cb + (size_t)row * DIM;
    float n = __fadd_rn(np_sumsq128(a), np_sumsq128(a + 128));
    g_norms[row] = n;
    atomicMax(&g_nkmax, __float_as_uint(n));
}

// bf16 convert + intra-row 16B-slot permutation: slot s -> s ^ (code&7)
__global__ void vq_prep_wb(const float* __restrict__ cb){
    int t = blockIdx.x * 256 + threadIdx.x;     // 262,144 = 8192 codes x 32 slots
    int code = t >> 5, s = t & 31;
    const float* src = cb + (size_t)code * DIM + s * 8;
    float4 v0 = *(const float4*)(src);
    float4 v1 = *(const float4*)(src + 4);
    u64* dst = (u64*)(g_wb + (size_t)code * DIM + ((s ^ (code & 7)) << 3));
    dst[0] = pack4(v0); dst[1] = pack4(v1);
}

__device__ __forceinline__ void ldsAtomicMinU64(u64* p, u64 v){
    u64 old = *p;
    while (v < old){
        u64 a = old;
        old = atomicCAS(p, a, v);
        if (old == a) break;
    }
}

__global__ __launch_bounds__(256, 4)
void vq_main(const float* __restrict__ z, const float* __restrict__ cb,
             float* __restrict__ out)
{
    __shared__ __align__(16) u16 Wst[2][CCH * DIM];   // 32,768 B double buffer
    __shared__ float t1[ROWS];
    __shared__ u32   rminU[ROWS];
    __shared__ u32   cnt[ROWS];
    __shared__ u16   cand[ROWS * CAP];                //  2,048 B
    __shared__ u16   taskRow[ROWS * CAP];             //  2,048 B
    __shared__ u64   bestKey[ROWS];
    __shared__ int   off[ROWS + 1];
    __shared__ int   totalS, ovf;                     // ~38.4 KB -> 4 blocks/CU

    const int tid     = threadIdx.x;                  // 256 threads, 4 waves
    const int rowbase = blockIdx.x * ROWS;
    const int w       = tid >> 6;                     // wave id -> 16-row group
    const int lane    = tid & 63;
    const int l15     = lane & 15, lg = lane >> 4;
    const int key     = l15 & 7;
    double lossAcc = 0.0;

    const float sqnkmax = sqrtf(__uint_as_float(g_nkmax));

    // ---- prologue: stage q0 chunk0; t1 from z; A-frags from z; reset ----
    {
        char* d = (char*)Wst[0];
#pragma unroll
        for (int r = 0; r < 4; ++r){
            int o = (r * 256 + tid) * 16;
            gload_lds16((const char*)g_wb + o, d + o);
        }
    }
    if (tid < 128){
        float s = np_sumsq128(z + (size_t)(rowbase + (tid >> 1)) * DIM
                              + (tid & 1) * 128);
        float o = __shfl_xor(s, 1);
        if (!(tid & 1)) t1[tid >> 1] = __fadd_rn(s, o);
    }
    if (tid < ROWS){
        rminU[tid]   = 0x7f800000u;
        cnt[tid]     = 0u;
        bestKey[tid] = ~0ull;
    }
    bf16x8 a[8];
    {
        const float* rr = z + (size_t)(rowbase + w * 16 + l15) * DIM + lg * 8;
#pragma unroll
        for (int ks = 0; ks < 8; ++ks){
            float4 v0 = *(const float4*)(rr + ks * 32);
            float4 v1 = *(const float4*)(rr + ks * 32 + 4);
            union { bf16x8 v; u64 p[2]; } u;
            u.p[0] = pack4(v0); u.p[1] = pack4(v1);
            a[ks] = u.v;
        }
    }
    __syncthreads();

    for (int q = 0; q < NQ; ++q){
        const float* rsrc = q ? (const float*)g_resid : z;
        const char*  wbq  = (const char*)g_wb + (size_t)q * KCODES * DIM * 2;
        const float* nrm  = g_norms + q * KCODES;

        float t1r[4], delta[4], mloc[4], thr[4];
#pragma unroll
        for (int j = 0; j < 4; ++j){
            t1r[j]   = t1[w * 16 + lg * 4 + j];
            delta[j] = 0.02f * sqrtf(t1r[j]) * sqnkmax + 3e-4f;
            mloc[j]  = __int_as_float(0x7f800000);
            thr[j]   = -1.0f;
        }

        // ---- chunk loop: 2 tiles/wave, dbuf, cadence-2 min sync ----
        for (int tt = 0; tt < NITER; ++tt){
            int  cc      = (tt < NCH) ? tt : (tt - NCH);
            int  cur     = tt & 1;
            bool collect = (tt >= WARM);

            if (tt >= 2 && (tt & 1) == 0){   // refresh thresholds
#pragma unroll
                for (int j = 0; j < 4; ++j){
                    float g = __uint_as_float(rminU[w * 16 + lg * 4 + j]);
                    thr[j] = fminf(g, mloc[j]) + delta[j];
                }
            }
            if (tt + 1 < NITER){             // issue-early: next chunk
                int nc = (tt + 1 < NCH) ? tt + 1 : (tt + 1 - NCH);
                const char* src = wbq + (size_t)nc * (CCH * DIM * 2);
                char* d = (char*)Wst[cur ^ 1];
#pragma unroll
                for (int r = 0; r < 4; ++r){
                    int o = (r * 256 + tid) * 16;
                    gload_lds16(src + o, d + o);
                }
            }

            // compute: 16 rows x 32 codes per wave (2 MFMA tiles)
            const u16* w0 = Wst[cur] + l15 * DIM;
            const u16* w1 = Wst[cur] + (16 + l15) * DIM;
            f32x4 acc0 = {0,0,0,0}, acc1 = {0,0,0,0};
#pragma unroll
            for (int ks = 0; ks < 8; ++ks){
                int so = ((ks * 4 + lg) ^ key) << 3;
                bf16x8 b0 = *(const bf16x8*)(w0 + so);
                bf16x8 b1 = *(const bf16x8*)(w1 + so);
                acc0 = __builtin_amdgcn_mfma_f32_16x16x32_bf16(a[ks], b0, acc0, 0, 0, 0);
                acc1 = __builtin_amdgcn_mfma_f32_16x16x32_bf16(a[ks], b1, acc1, 0, 0, 0);
            }
            float nk0 = nrm[cc * CCH + l15];
            float nk1 = nrm[cc * CCH + 16 + l15];
#pragma unroll
            for (int j = 0; j < 4; ++j){
                int   row = w * 16 + lg * 4 + j;
                float d0  = (t1r[j] + nk0) - 2.0f * acc0[j];
                float d1  = (t1r[j] + nk1) - 2.0f * acc1[j];
                mloc[j] = fminf(mloc[j], fminf(d0, d1));
                if (collect){
                    if (d0 <= thr[j]){
                        u32 slot = atomicAdd(&cnt[row], 1u);
                        if (slot < CAP) cand[row * CAP + slot] = (u16)(cc * CCH + l15);
                    }
                    if (d1 <= thr[j]){
                        u32 slot = atomicAdd(&cnt[row], 1u);
                        if (slot < CAP) cand[row * CAP + slot] = (u16)(cc * CCH + 16 + l15);
                    }
                }
            }
            if ((tt & 1) == 1){              // publish wave-min to rminU
                float m[4];
#pragma unroll
                for (int j = 0; j < 4; ++j) m[j] = mloc[j];
#pragma unroll
                for (int msk = 1; msk < 16; msk <<= 1)
#pragma unroll
                    for (int j = 0; j < 4; ++j)
                        m[j] = fminf(m[j], __shfl_xor(m[j], msk));
                if (l15 == 0){
#pragma unroll
                    for (int j = 0; j < 4; ++j)
                        atomicMin(&rminU[w * 16 + lg * 4 + j],
                                  __float_as_uint(m[j]));
                }
            }
            __syncthreads();
        }

        // ---- offsets scan (wave 0) + taskRow fill ----
        if (tid < 64){
            int c    = min((int)cnt[tid], CAP);
            int over = cnt[tid] > CAP;
            int x = c;
#pragma unroll
            for (int o = 1; o < 64; o <<= 1){
                int y = __shfl_up(x, o);
                if (tid >= o) x += y;
            }
            off[tid] = x - c;
            if (tid == 63){ off[64] = x; totalS = x; }
#pragma unroll
            for (int o = 1; o < 64; o <<= 1) over |= __shfl_xor(over, o);
            if (tid == 0) ovf = over;
        }
        __syncthreads();
        if (tid < 64){
            int b = off[tid], e = off[tid + 1];
            for (int i = b; i < e; ++i) taskRow[i] = (u16)tid;
        }
        __syncthreads();

        // ---- exact rescore (round-4-identical serial FMA chain) ----
        int nT = totalS;
        for (int t = tid; t < nT; t += 256){
            int r = taskRow[t];
            int k = (int)cand[r * CAP + (t - off[r])];
            const float* wr = cb + ((size_t)q * KCODES + k) * DIM;
            const float* rr = rsrc + (size_t)(rowbase + r) * DIM;
            float dot = 0.f;
#pragma unroll 4
            for (int i = 0; i < 64; ++i){
                float4 rv = *(const float4*)(rr + i * 4);
                float4 wv = *(const float4*)(wr + i * 4);
                dot = __builtin_fmaf(rv.x, wv.x, dot);
                dot = __builtin_fmaf(rv.y, wv.y, dot);
                dot = __builtin_fmaf(rv.z, wv.z, dot);
                dot = __builtin_fmaf(rv.w, wv.w, dot);
            }
            float d = __fsub_rn(__fadd_rn(t1[r], nrm[k]), __fmul_rn(2.0f, dot));
            ldsAtomicMinU64(&bestKey[r], ((u64)__float_as_uint(d) << 32) | (u32)k);
        }
        if (ovf){   // correctness fallback; rare
            for (int r = 0; r < ROWS; ++r){
                if (cnt[r] > CAP){
                    for (int k = tid; k < KCODES; k += 256){
                        const float* wr = cb + ((size_t)q * KCODES + k) * DIM;
                        const float* rr = rsrc + (size_t)(rowbase + r) * DIM;
                        float dot = 0.f;
                        for (int i = 0; i < 64; ++i){
                            float4 rv = *(const float4*)(rr + i * 4);
                            float4 wv = *(const float4*)(wr + i * 4);
                            dot = __builtin_fmaf(rv.x, wv.x, dot);
                            dot = __builtin_fmaf(rv.y, wv.y, dot);
                            dot = __builtin_fmaf(rv.z, wv.z, dot);
                            dot = __builtin_fmaf(rv.w, wv.w, dot);
                        }
                        float d = __fsub_rn(__fadd_rn(t1[r], nrm[k]),
                                            __fmul_rn(2.0f, dot));
                        ldsAtomicMinU64(&bestKey[r], ((u64)__float_as_uint(d) << 32) | (u32)k);
                    }
                }
            }
        }
        __syncthreads();

        // indices out (f32)
        if (tid < ROWS)
            out[(size_t)NVEC * DIM + (size_t)(rowbase + tid) * NQ + q] =
                (float)(int)(bestKey[tid] & 0xFFFFFFFFull);

        // stage next-q chunk0 under the update (drains at the barrier below)
        if (q + 1 < NQ){
            const char* nwbq = wbq + (size_t)KCODES * DIM * 2;
            char* d = (char*)Wst[0];
#pragma unroll
            for (int r = 0; r < 4; ++r){
                int o = (r * 256 + tid) * 16;
                gload_lds16(nwbq + o, d + o);
            }
        }

        // ---- fused update + np-exact t1 (+ recon at q=7) ----
        if (tid < 128){
            int row = tid >> 1, h = tid & 1;
            int k   = (int)(bestKey[row] & 0xFFFFFFFFull);
            size_t rb = (size_t)(rowbase + row) * DIM + h * 128;
            const float* wrow = cb + ((size_t)q * KCODES + k) * DIM + h * 128;
            const float* rrow = rsrc + rb;
            float ac[8];
#pragma unroll 8
            for (int j = 0; j < 32; ++j){
                float4 r4 = *(const float4*)(rrow + j * 4);
                float4 wv = *(const float4*)(wrow + j * 4);
                float4 rn;
                rn.x = __fsub_rn(r4.x, __fadd_rn(r4.x, __fsub_rn(wv.x, r4.x)));
                rn.y = __fsub_rn(r4.y, __fadd_rn(r4.y, __fsub_rn(wv.y, r4.y)));
                rn.z = __fsub_rn(r4.z, __fadd_rn(r4.z, __fsub_rn(wv.z, r4.z)));
                rn.w = __fsub_rn(r4.w, __fadd_rn(r4.w, __fsub_rn(wv.w, r4.w)));
                if (q + 1 < NQ){
                    *(float4*)(g_resid + rb + j * 4) = rn;
                    *(u64*)(g_residb + rb + j * 4)   = pack4(rn);
                } else {
                    float4 zv = *(const float4*)(z + rb + j * 4);
                    float4 ov;
                    ov.x = __fsub_rn(zv.x, rn.x);
                    ov.y = __fsub_rn(zv.y, rn.y);
                    ov.z = __fsub_rn(zv.z, rn.z);
                    ov.w = __fsub_rn(zv.w, rn.w);
                    *(float4*)(out + rb + j * 4) = ov;
                }
                int c0 = (j & 1) * 4;   // np tree: acc index = col mod 8
                if (j < 2){
                    ac[c0+0] = __fmul_rn(rn.x, rn.x);
                    ac[c0+1] = __fmul_rn(rn.y, rn.y);
                    ac[c0+2] = __fmul_rn(rn.z, rn.z);
                    ac[c0+3] = __fmul_rn(rn.w, rn.w);
                } else {
                    ac[c0+0] = __fadd_rn(ac[c0+0], __fmul_rn(rn.x, rn.x));
                    ac[c0+1] = __fadd_rn(ac[c0+1], __fmul_rn(rn.y, rn.y));
                    ac[c0+2] = __fadd_rn(ac[c0+2], __fmul_rn(rn.z, rn.z));
                    ac[c0+3] = __fadd_rn(ac[c0+3], __fmul_rn(rn.w, rn.w));
                }
            }
            float half = __fadd_rn(__fadd_rn(__fadd_rn(ac[0],ac[1]), __fadd_rn(ac[2],ac[3])),
                                   __fadd_rn(__fadd_rn(ac[4],ac[5]), __fadd_rn(ac[6],ac[7])));
            float o = __shfl_xor(half, 1);
            if (!h) t1[row] = __fadd_rn(half, o);   // lo + hi (np order)
        }
        __syncthreads();   // t1/g_resid/g_residb visible; stage0 drained

        // loss += sum(t1) (wave 0); r_{q+1} norms, q=0..7 -> 8 terms total
        if (tid < 64){
            float s = t1[tid];
#pragma unroll
            for (int o = 1; o < 64; o <<= 1) s += __shfl_xor(s, o);
            if (tid == 0) lossAcc += (double)s;
        }

        // A-frags for next q from bf16 shadow; reset per-row state
        if (q + 1 < NQ){
            const u16* rr = g_residb + (size_t)(rowbase + w * 16 + l15) * DIM + lg * 8;
#pragma unroll
            for (int ks = 0; ks < 8; ++ks)
                a[ks] = *(const bf16x8*)(rr + ks * 32);
            if (tid < ROWS){
                rminU[tid]   = 0x7f800000u;
                cnt[tid]     = 0u;
                bestKey[tid] = ~0ull;
            }
        }
        __syncthreads();
    }

    if (tid == 0) atomicAdd(&g_loss, lossAcc);
}

__global__ void vq_loss_final(float* __restrict__ out){
    if (threadIdx.x == 0 && blockIdx.x == 0){
        double m = 1.25 * g_loss / ((double)NVEC * (double)DIM);
        out[(size_t)NVEC * DIM + (size_t)NVEC * NQ] = (float)m;
    }
}

extern "C" void kernel_launch(void* const* d_in, const int* in_sizes, int n_in,
                              void* d_out, int out_size, void* d_ws, size_t ws_size,
                              hipStream_t stream) {
    (void)in_sizes; (void)n_in; (void)out_size; (void)d_ws; (void)ws_size;
    const float* z  = (const float*)d_in[0];
    const float* cb = (const float*)d_in[1];
    float* out = (float*)d_out;

    hipLaunchKernelGGL(vq_zero,       dim3(1),    dim3(1),   0, stream);
    hipLaunchKernelGGL(vq_norms_np,   dim3(32),   dim3(256), 0, stream, cb);
    hipLaunchKernelGGL(vq_prep_wb,    dim3(1024), dim3(256), 0, stream, cb);
    hipLaunchKernelGGL(vq_main,       dim3(NVEC / ROWS), dim3(256), 0, stream, z, cb, out);
    hipLaunchKernelGGL(vq_loss_final, dim3(1),    dim3(64),  0, stream, out);
}

// Round 13
// 2042.082 us; speedup vs baseline: 1.1548x; 1.1548x over previous
//
#include <hip/hip_runtime.h>
#include <stdint.h>

// ResidualVQ on MI355X — round 13: r11's coalesced phases + r12's cheap loop.
// - update: 256 thr, 4 thr/row, d0=us*4+j*16 (64B/quad coalesced; r12's
//   512B-stride half-row streaming caused 5GB HBM -> reverted).
// - t1: separate np-exact pass (np 8-acc fold can't split across lanes).
// - chunk loop: CCH=32, 2 MFMA tiles/wave, 34 barriers/q, taskRow LUT,
//   next-q chunk0 prefetch (all from r12 — these were fine).
// - g_residb bf16 shadow (coalesced write in update) feeds A-frags;
//   q=7 update writes recon directly (+ g_resid for final loss pass).
// Contract (proven rounds 4-12): indices match numpy argmin of
// d = fl(fl(t1+nk) - fl(2*dot)); np-exact pairwise sumsq trees; serial
// ascending-k single-accumulator FMA rescore; stale-threshold prefilter,
// delta = 0.02*sqrt(t1)*sqrt(nkmax) + 3e-4 >= 2*E_bf16.
// g_wb PRE-PERMUTED (16B slot s -> s^(code&7) per 512B code row).

#define NQ      8
#define KCODES  1024
#define DIM     256
#define NVEC    65536
#define ROWS    64
#define CCH     32       // codes per staged chunk (16 KB per buffer)
#define NCH     (KCODES / CCH)   // 32 chunks
#define WARM    2
#define NITER   (NCH + WARM)     // 34
#define CAP     16       // candidate capacity per row per q

typedef unsigned int u32;
typedef unsigned long long u64;
typedef unsigned short u16;
typedef short bf16x8 __attribute__((ext_vector_type(8)));
typedef float f32x4  __attribute__((ext_vector_type(4)));

__device__ float  g_norms[NQ * KCODES];
__device__ u32    g_nkmax;
__device__ double g_loss;
__device__ __align__(16) u16 g_wb[(size_t)NQ * KCODES * DIM];  // permuted bf16
__device__ float  g_resid[(size_t)NVEC * DIM];                 // f32 residual
__device__ __align__(16) u16 g_residb[(size_t)NVEC * DIM];     // bf16 shadow

__device__ __forceinline__ u16 bf16rne(float x){
    u32 u = __float_as_uint(x);
    return (u16)((u + 0x7FFFu + ((u >> 16) & 1u)) >> 16);
}

__device__ __forceinline__ u64 pack4(float4 v){
    return  (u64)bf16rne(v.x)        | ((u64)bf16rne(v.y) << 16)
         | ((u64)bf16rne(v.z) << 32) | ((u64)bf16rne(v.w) << 48);
}

__device__ __forceinline__ void gload_lds16(const void* g, void* l){
    __builtin_amdgcn_global_load_lds(
        (const __attribute__((address_space(1))) u32*)g,
        (__attribute__((address_space(3))) u32*)l, 16, 0, 0);
}

// numpy pairwise sum of squares over 128 contiguous floats (verified round 4)
__device__ __forceinline__ float np_sumsq128(const float* __restrict__ a){
    float r0,r1,r2,r3,r4,r5,r6,r7;
    {
        float4 v0 = *(const float4*)(a);
        float4 v1 = *(const float4*)(a + 4);
        r0 = __fmul_rn(v0.x,v0.x); r1 = __fmul_rn(v0.y,v0.y);
        r2 = __fmul_rn(v0.z,v0.z); r3 = __fmul_rn(v0.w,v0.w);
        r4 = __fmul_rn(v1.x,v1.x); r5 = __fmul_rn(v1.y,v1.y);
        r6 = __fmul_rn(v1.z,v1.z); r7 = __fmul_rn(v1.w,v1.w);
    }
    for (int i = 8; i < 128; i += 8){
        float4 v0 = *(const float4*)(a + i);
        float4 v1 = *(const float4*)(a + i + 4);
        r0 = __fadd_rn(r0, __fmul_rn(v0.x,v0.x));
        r1 = __fadd_rn(r1, __fmul_rn(v0.y,v0.y));
        r2 = __fadd_rn(r2, __fmul_rn(v0.z,v0.z));
        r3 = __fadd_rn(r3, __fmul_rn(v0.w,v0.w));
        r4 = __fadd_rn(r4, __fmul_rn(v1.x,v1.x));
        r5 = __fadd_rn(r5, __fmul_rn(v1.y,v1.y));
        r6 = __fadd_rn(r6, __fmul_rn(v1.z,v1.z));
        r7 = __fadd_rn(r7, __fmul_rn(v1.w,v1.w));
    }
    return __fadd_rn(__fadd_rn(__fadd_rn(r0,r1), __fadd_rn(r2,r3)),
                     __fadd_rn(__fadd_rn(r4,r5), __fadd_rn(r6,r7)));
}

__global__ void vq_zero(){ g_loss = 0.0; g_nkmax = 0u; }

__global__ void vq_norms_np(const float* __restrict__ cb){
    int row = blockIdx.x * 256 + threadIdx.x;               // 8192 rows
    const float* a = cb + (size_t)row * DIM;
    float n = __fadd_rn(np_sumsq128(a), np_sumsq128(a + 128));
    g_norms[row] = n;
    atomicMax(&g_nkmax, __float_as_uint(n));
}

// bf16 convert + intra-row 16B-slot permutation: slot s -> s ^ (code&7)
__global__ void vq_prep_wb(const float* __restrict__ cb){
    int t = blockIdx.x * 256 + threadIdx.x;     // 262,144 = 8192 codes x 32 slots
    int code = t >> 5, s = t & 31;
    const float* src = cb + (size_t)code * DIM + s * 8;
    float4 v0 = *(const float4*)(src);
    float4 v1 = *(const float4*)(src + 4);
    u64* dst = (u64*)(g_wb + (size_t)code * DIM + ((s ^ (code & 7)) << 3));
    dst[0] = pack4(v0); dst[1] = pack4(v1);
}

__device__ __forceinline__ void ldsAtomicMinU64(u64* p, u64 v){
    u64 old = *p;
    while (v < old){
        u64 a = old;
        old = atomicCAS(p, a, v);
        if (old == a) break;
    }
}

__global__ __launch_bounds__(256, 4)
void vq_main(const float* __restrict__ z, const float* __restrict__ cb,
             float* __restrict__ out)
{
    __shared__ __align__(16) u16 Wst[2][CCH * DIM];   // 32,768 B double buffer
    __shared__ float t1[ROWS];
    __shared__ u32   rminU[ROWS];
    __shared__ u32   cnt[ROWS];
    __shared__ u16   cand[ROWS * CAP];                //  2,048 B
    __shared__ u16   taskRow[ROWS * CAP];             //  2,048 B
    __shared__ u64   bestKey[ROWS];
    __shared__ int   off[ROWS + 1];
    __shared__ int   totalS, ovf;                     // ~38.4 KB -> 4 blocks/CU

    const int tid     = threadIdx.x;                  // 256 threads, 4 waves
    const int rowbase = blockIdx.x * ROWS;
    const int w       = tid >> 6;                     // wave id -> 16-row group
    const int lane    = tid & 63;
    const int l15     = lane & 15, lg = lane >> 4;
    const int key     = l15 & 7;
    const int urow    = tid >> 2, us = tid & 3;       // update map: 4 thr/row
    double lossAcc = 0.0;

    const float sqnkmax = sqrtf(__uint_as_float(g_nkmax));

    // prologue: stage q0 chunk0 -> buf0
    {
        char* d = (char*)Wst[0];
#pragma unroll
        for (int r = 0; r < 4; ++r){
            int o = (r * 256 + tid) * 16;
            gload_lds16((const char*)g_wb + o, d + o);
        }
    }

    for (int q = 0; q < NQ; ++q){
        const float* rsrc = q ? (const float*)g_resid : z;
        const char*  wbq  = (const char*)g_wb + (size_t)q * KCODES * DIM * 2;
        const float* nrm  = g_norms + q * KCODES;

        // ---- t1 (np-exact) + state reset + A-frags ----
        if (tid < 128){
            float s = np_sumsq128(rsrc + (size_t)(rowbase + (tid >> 1)) * DIM
                                  + (tid & 1) * 128);
            float o = __shfl_xor(s, 1);
            if (!(tid & 1)) t1[tid >> 1] = __fadd_rn(s, o);
        }
        if (tid < ROWS){
            rminU[tid]   = 0x7f800000u;
            cnt[tid]     = 0u;
            bestKey[tid] = ~0ull;
        }
        bf16x8 a[8];
        if (q == 0){
            const float* rr = z + (size_t)(rowbase + w * 16 + l15) * DIM + lg * 8;
#pragma unroll
            for (int ks = 0; ks < 8; ++ks){
                float4 v0 = *(const float4*)(rr + ks * 32);
                float4 v1 = *(const float4*)(rr + ks * 32 + 4);
                union { bf16x8 v; u64 p[2]; } u;
                u.p[0] = pack4(v0); u.p[1] = pack4(v1);
                a[ks] = u.v;
            }
        } else {
            const u16* rr = g_residb + (size_t)(rowbase + w * 16 + l15) * DIM + lg * 8;
#pragma unroll
            for (int ks = 0; ks < 8; ++ks)
                a[ks] = *(const bf16x8*)(rr + ks * 32);
        }
        __syncthreads();    // t1 ready; chunk0 stage drained

        if (q > 0 && tid < 64){         // loss += ||r_q||^2
            float s = t1[tid];
#pragma unroll
            for (int o = 1; o < 64; o <<= 1) s += __shfl_xor(s, o);
            if (tid == 0) lossAcc += (double)s;
        }

        float t1r[4], delta[4], mloc[4], thr[4];
#pragma unroll
        for (int j = 0; j < 4; ++j){
            t1r[j]   = t1[w * 16 + lg * 4 + j];
            delta[j] = 0.02f * sqrtf(t1r[j]) * sqnkmax + 3e-4f;
            mloc[j]  = __int_as_float(0x7f800000);
            thr[j]   = -1.0f;
        }

        // ---- chunk loop: 2 tiles/wave, dbuf, cadence-2 min sync ----
        for (int tt = 0; tt < NITER; ++tt){
            int  cc      = (tt < NCH) ? tt : (tt - NCH);
            int  cur     = tt & 1;
            bool collect = (tt >= WARM);

            if (tt >= 2 && (tt & 1) == 0){
#pragma unroll
                for (int j = 0; j < 4; ++j){
                    float g = __uint_as_float(rminU[w * 16 + lg * 4 + j]);
                    thr[j] = fminf(g, mloc[j]) + delta[j];
                }
            }
            if (tt + 1 < NITER){
                int nc = (tt + 1 < NCH) ? tt + 1 : (tt + 1 - NCH);
                const char* src = wbq + (size_t)nc * (CCH * DIM * 2);
                char* d = (char*)Wst[cur ^ 1];
#pragma unroll
                for (int r = 0; r < 4; ++r){
                    int o = (r * 256 + tid) * 16;
                    gload_lds16(src + o, d + o);
                }
            }

            const u16* w0 = Wst[cur] + l15 * DIM;
            const u16* w1 = Wst[cur] + (16 + l15) * DIM;
            f32x4 acc0 = {0,0,0,0}, acc1 = {0,0,0,0};
#pragma unroll
            for (int ks = 0; ks < 8; ++ks){
                int so = ((ks * 4 + lg) ^ key) << 3;
                bf16x8 b0 = *(const bf16x8*)(w0 + so);
                bf16x8 b1 = *(const bf16x8*)(w1 + so);
                acc0 = __builtin_amdgcn_mfma_f32_16x16x32_bf16(a[ks], b0, acc0, 0, 0, 0);
                acc1 = __builtin_amdgcn_mfma_f32_16x16x32_bf16(a[ks], b1, acc1, 0, 0, 0);
            }
            float nk0 = nrm[cc * CCH + l15];
            float nk1 = nrm[cc * CCH + 16 + l15];
#pragma unroll
            for (int j = 0; j < 4; ++j){
                int   row = w * 16 + lg * 4 + j;
                float d0  = (t1r[j] + nk0) - 2.0f * acc0[j];
                float d1  = (t1r[j] + nk1) - 2.0f * acc1[j];
                mloc[j] = fminf(mloc[j], fminf(d0, d1));
                if (collect){
                    if (d0 <= thr[j]){
                        u32 slot = atomicAdd(&cnt[row], 1u);
                        if (slot < CAP) cand[row * CAP + slot] = (u16)(cc * CCH + l15);
                    }
                    if (d1 <= thr[j]){
                        u32 slot = atomicAdd(&cnt[row], 1u);
                        if (slot < CAP) cand[row * CAP + slot] = (u16)(cc * CCH + 16 + l15);
                    }
                }
            }
            if ((tt & 1) == 1){
                float m[4];
#pragma unroll
                for (int j = 0; j < 4; ++j) m[j] = mloc[j];
#pragma unroll
                for (int msk = 1; msk < 16; msk <<= 1)
#pragma unroll
                    for (int j = 0; j < 4; ++j)
                        m[j] = fminf(m[j], __shfl_xor(m[j], msk));
                if (l15 == 0){
#pragma unroll
                    for (int j = 0; j < 4; ++j)
                        atomicMin(&rminU[w * 16 + lg * 4 + j],
                                  __float_as_uint(m[j]));
                }
            }
            __syncthreads();
        }

        // ---- offsets scan (wave 0) ----
        if (tid < 64){
            int c    = min((int)cnt[tid], CAP);
            int over = cnt[tid] > CAP;
            int x = c;
#pragma unroll
            for (int o = 1; o < 64; o <<= 1){
                int y = __shfl_up(x, o);
                if (tid >= o) x += y;
            }
            off[tid] = x - c;
            if (tid == 63){ off[64] = x; totalS = x; }
#pragma unroll
            for (int o = 1; o < 64; o <<= 1) over |= __shfl_xor(over, o);
            if (tid == 0) ovf = over;
        }
        __syncthreads();
        if (tid < 64){
            int b = off[tid], e = off[tid + 1];
            for (int i = b; i < e; ++i) taskRow[i] = (u16)tid;
        }
        __syncthreads();

        // ---- exact rescore (round-4-identical serial FMA chain) ----
        int nT = totalS;
        for (int t = tid; t < nT; t += 256){
            int r = taskRow[t];
            int k = (int)cand[r * CAP + (t - off[r])];
            const float* wr = cb + ((size_t)q * KCODES + k) * DIM;
            const float* rr = rsrc + (size_t)(rowbase + r) * DIM;
            float dot = 0.f;
#pragma unroll 4
            for (int i = 0; i < 64; ++i){
                float4 rv = *(const float4*)(rr + i * 4);
                float4 wv = *(const float4*)(wr + i * 4);
                dot = __builtin_fmaf(rv.x, wv.x, dot);
                dot = __builtin_fmaf(rv.y, wv.y, dot);
                dot = __builtin_fmaf(rv.z, wv.z, dot);
                dot = __builtin_fmaf(rv.w, wv.w, dot);
            }
            float d = __fsub_rn(__fadd_rn(t1[r], nrm[k]), __fmul_rn(2.0f, dot));
            ldsAtomicMinU64(&bestKey[r], ((u64)__float_as_uint(d) << 32) | (u32)k);
        }
        if (ovf){   // correctness fallback; rare
            for (int r = 0; r < ROWS; ++r){
                if (cnt[r] > CAP){
                    for (int k = tid; k < KCODES; k += 256){
                        const float* wr = cb + ((size_t)q * KCODES + k) * DIM;
                        const float* rr = rsrc + (size_t)(rowbase + r) * DIM;
                        float dot = 0.f;
                        for (int i = 0; i < 64; ++i){
                            float4 rv = *(const float4*)(rr + i * 4);
                            float4 wv = *(const float4*)(wr + i * 4);
                            dot = __builtin_fmaf(rv.x, wv.x, dot);
                            dot = __builtin_fmaf(rv.y, wv.y, dot);
                            dot = __builtin_fmaf(rv.z, wv.z, dot);
                            dot = __builtin_fmaf(rv.w, wv.w, dot);
                        }
                        float d = __fsub_rn(__fadd_rn(t1[r], nrm[k]),
                                            __fmul_rn(2.0f, dot));
                        ldsAtomicMinU64(&bestKey[r], ((u64)__float_as_uint(d) << 32) | (u32)k);
                    }
                }
            }
        }
        __syncthreads();

        // indices out (f32)
        if (tid < ROWS)
            out[(size_t)NVEC * DIM + (size_t)(rowbase + tid) * NQ + q] =
                (float)(int)(bestKey[tid] & 0xFFFFFFFFull);

        // stage next-q chunk0 under the update (drains at the barrier below)
        if (q + 1 < NQ){
            const char* nwbq = wbq + (size_t)KCODES * DIM * 2;
            char* d = (char*)Wst[0];
#pragma unroll
            for (int r = 0; r < 4; ++r){
                int o = (r * 256 + tid) * 16;
                gload_lds16(nwbq + o, d + o);
            }
        }

        // ---- update (coalesced, 4 thr/row): r_new = fl(r - fl(r + fl(zq-r)))
        {
            int k = (int)(bestKey[urow] & 0xFFFFFFFFull);
            const float* wrow = cb + ((size_t)q * KCODES + k) * DIM;
            size_t rb = (size_t)(rowbase + urow) * DIM;
            const float* rrow = rsrc + rb;
#pragma unroll
            for (int j = 0; j < 16; ++j){
                int d0 = us * 4 + j * 16;
                float4 r4 = *(const float4*)(rrow + d0);
                float4 wv = *(const float4*)(wrow + d0);
                float4 rn;
                rn.x = __fsub_rn(r4.x, __fadd_rn(r4.x, __fsub_rn(wv.x, r4.x)));
                rn.y = __fsub_rn(r4.y, __fadd_rn(r4.y, __fsub_rn(wv.y, r4.y)));
                rn.z = __fsub_rn(r4.z, __fadd_rn(r4.z, __fsub_rn(wv.z, r4.z)));
                rn.w = __fsub_rn(r4.w, __fadd_rn(r4.w, __fsub_rn(wv.w, r4.w)));
                *(float4*)(g_resid + rb + d0) = rn;
                if (q + 1 < NQ){
                    *(u64*)(g_residb + rb + d0) = pack4(rn);
                } else {
                    float4 zv = *(const float4*)(z + rb + d0);
                    float4 ov;
                    ov.x = __fsub_rn(zv.x, rn.x);
                    ov.y = __fsub_rn(zv.y, rn.y);
                    ov.z = __fsub_rn(zv.z, rn.z);
                    ov.w = __fsub_rn(zv.w, rn.w);
                    *(float4*)(out + rb + d0) = ov;
                }
            }
        }
        __syncthreads();   // g_resid/g_residb visible; next-q stage0 drained
    }

    // final ||r_8||^2 -> loss
    if (tid < 128){
        float s = np_sumsq128(g_resid + (size_t)(rowbase + (tid >> 1)) * DIM
                              + (tid & 1) * 128);
        float o = __shfl_xor(s, 1);
        if (!(tid & 1)) t1[tid >> 1] = __fadd_rn(s, o);
    }
    __syncthreads();
    if (tid < 64){
        float s = t1[tid];
#pragma unroll
        for (int o = 1; o < 64; o <<= 1) s += __shfl_xor(s, o);
        if (tid == 0){ lossAcc += (double)s; atomicAdd(&g_loss, lossAcc); }
    }
}

__global__ void vq_loss_final(float* __restrict__ out){
    if (threadIdx.x == 0 && blockIdx.x == 0){
        double m = 1.25 * g_loss / ((double)NVEC * (double)DIM);
        out[(size_t)NVEC * DIM + (size_t)NVEC * NQ] = (float)m;
    }
}

extern "C" void kernel_launch(void* const* d_in, const int* in_sizes, int n_in,
                              void* d_out, int out_size, void* d_ws, size_t ws_size,
                              hipStream_t stream) {
    (void)in_sizes; (void)n_in; (void)out_size; (void)d_ws; (void)ws_size;
    const float* z  = (const float*)d_in[0];
    const float* cb = (const float*)d_in[1];
    float* out = (float*)d_out;

    hipLaunchKernelGGL(vq_zero,       dim3(1),    dim3(1),   0, stream);
    hipLaunchKernelGGL(vq_norms_np,   dim3(32),   dim3(256), 0, stream, cb);
    hipLaunchKernelGGL(vq_prep_wb,    dim3(1024), dim3(256), 0, stream, cb);
    hipLaunchKernelGGL(vq_main,       dim3(NVEC / ROWS), dim3(256), 0, stream, z, cb, out);
    hipLaunchKernelGGL(vq_loss_final, dim3(1),    dim3(64),  0, stream, out);
}